// Round 1
// baseline (1644.623 us; speedup 1.0000x reference)
//
#include <hip/hip_runtime.h>
#include <math.h>

#define TSTEPS 6
#define NN 20000
#define NE 320000
#define INF 11
#define HID 64
#define OUTF 3

// ---------------- graph-structure kernels (once per call) ----------------

__global__ void k_deg(const int* __restrict__ src, float* __restrict__ deg, int E) {
    int e = blockIdx.x * blockDim.x + threadIdx.x;
    if (e < E) atomicAdd(&deg[src[e]], 1.0f);
}

__global__ void k_dis(float* deg, int n) {
    int i = blockIdx.x * blockDim.x + threadIdx.x;
    if (i < n) {
        float d = deg[i];
        deg[i] = d > 0.0f ? rsqrtf(fmaxf(d, 1.0f)) : 0.0f;
    }
}

__global__ void k_ew(const int* __restrict__ src, const int* __restrict__ dst,
                     const float* __restrict__ dis, float* __restrict__ ew, int E) {
    int e = blockIdx.x * blockDim.x + threadIdx.x;
    if (e < E) ew[e] = -dis[src[e]] * dis[dst[e]];
}

// ---------------- per-timestep kernels ----------------

// t == 0: x_in = X_seq[0]
__global__ void k_xin0(const float* __restrict__ Xt, float* __restrict__ xin, int n) {
    int i = blockIdx.x * blockDim.x + threadIdx.x;
    if (i < n * INF) xin[i] = Xt[i];
}

// t > 0: x_in = X_seq[t] with cols 3:6 <- u_prev, cols 8:11 <- (u_prev - X_prev[:,3:6]) / dt
__global__ void k_xin(const float* __restrict__ Xt, const float* __restrict__ Xp,
                      const float* __restrict__ uprev, float* __restrict__ xin, int n) {
    int i = blockIdx.x * blockDim.x + threadIdx.x;
    if (i >= n) return;
    const float* xt = Xt + (size_t)i * INF;
    const float* xp = Xp + (size_t)i * INF;
    const float* up = uprev + (size_t)i * OUTF;
    float* xo = xin + (size_t)i * INF;
    float dt = xt[6] - xp[6];
    float inv = 1.0f / dt;
    xo[0] = xt[0]; xo[1] = xt[1]; xo[2] = xt[2];
    xo[3] = up[0]; xo[4] = up[1]; xo[5] = up[2];
    xo[6] = xt[6]; xo[7] = xt[7];
    xo[8] = (up[0] - xp[3]) * inv;
    xo[9] = (up[1] - xp[4]) * inv;
    xo[10] = (up[2] - xp[5]) * inv;
}

// scatter for 11-wide features: out[dst] += ew * x[src]
__global__ void k_scat11(const int* __restrict__ src, const int* __restrict__ dst,
                         const float* __restrict__ ew, const float* __restrict__ x,
                         float* __restrict__ out, int E) {
    int tid = blockIdx.x * blockDim.x + threadIdx.x;
    if (tid >= E * INF) return;
    int e = tid / INF;
    int i = tid - e * INF;
    float v = ew[e] * x[(size_t)src[e] * INF + i];
    atomicAdd(&out[(size_t)dst[e] * INF + i], v);
}

// scatter for 64-wide features: out[dst] += ew * x[src]; thread = (edge, f)
__global__ void k_scat64(const int* __restrict__ src, const int* __restrict__ dst,
                         const float* __restrict__ ew, const float* __restrict__ x,
                         float* __restrict__ out, int E) {
    int tid = blockIdx.x * blockDim.x + threadIdx.x;
    int e = tid >> 6;
    int f = tid & 63;
    if (e >= E) return;
    float v = ew[e] * x[(size_t)src[e] * HID + f];
    atomicAdd(&out[(size_t)dst[e] * HID + f], v);
}

// Z/R gate kernel: one wave per node, lane f = output channel.
__global__ __launch_bounds__(256) void k_gates(
    const float* __restrict__ xin, const float* __restrict__ t1x,
    const float* __restrict__ h, const float* __restrict__ t1h,
    const float* __restrict__ Wx, const float* __restrict__ bx,
    const float* __restrict__ Wh, const float* __restrict__ bh,
    float* __restrict__ Zb, float* __restrict__ hr, int n) {
    int wave = (int)((blockIdx.x * blockDim.x + threadIdx.x) >> 6);
    int f = threadIdx.x & 63;
    if (wave >= n) return;
    const float* xr = xin + (size_t)wave * INF;
    const float* tr = t1x + (size_t)wave * INF;
    float az = bx[0 * HID + f] + bh[0 * HID + f];
    float ar = bx[1 * HID + f] + bh[1 * HID + f];
#pragma unroll
    for (int i = 0; i < INF; ++i) {
        float xv = xr[i], tv = tr[i];
        az = fmaf(xv, Wx[((0 * 2 + 0) * INF + i) * HID + f], az);
        az = fmaf(tv, Wx[((0 * 2 + 1) * INF + i) * HID + f], az);
        ar = fmaf(xv, Wx[((1 * 2 + 0) * INF + i) * HID + f], ar);
        ar = fmaf(tv, Wx[((1 * 2 + 1) * INF + i) * HID + f], ar);
    }
    float hv = h[(size_t)wave * HID + f];
    float th = t1h[(size_t)wave * HID + f];
#pragma unroll 8
    for (int j = 0; j < HID; ++j) {
        float hj = __shfl(hv, j);
        float tj = __shfl(th, j);
        az = fmaf(hj, Wh[((0 * 2 + 0) * HID + j) * HID + f], az);
        az = fmaf(tj, Wh[((0 * 2 + 1) * HID + j) * HID + f], az);
        ar = fmaf(hj, Wh[((1 * 2 + 0) * HID + j) * HID + f], ar);
        ar = fmaf(tj, Wh[((1 * 2 + 1) * HID + j) * HID + f], ar);
    }
    float Z = 1.0f / (1.0f + expf(-az));
    float R = 1.0f / (1.0f + expf(-ar));
    Zb[(size_t)wave * HID + f] = Z;
    hr[(size_t)wave * HID + f] = hv * R;
}

// Candidate + blend kernel: Ht = tanh(...), h_new = Z*h + (1-Z)*Ht (in place on h)
__global__ __launch_bounds__(256) void k_cand(
    const float* __restrict__ xin, const float* __restrict__ t1x,
    float* __restrict__ h, const float* __restrict__ hr,
    const float* __restrict__ t1hr,
    const float* __restrict__ Wx, const float* __restrict__ bx,
    const float* __restrict__ Wh, const float* __restrict__ bh,
    const float* __restrict__ Zb, int n) {
    int wave = (int)((blockIdx.x * blockDim.x + threadIdx.x) >> 6);
    int f = threadIdx.x & 63;
    if (wave >= n) return;
    const float* xr = xin + (size_t)wave * INF;
    const float* tr = t1x + (size_t)wave * INF;
    float ah = bx[2 * HID + f] + bh[2 * HID + f];
#pragma unroll
    for (int i = 0; i < INF; ++i) {
        float xv = xr[i], tv = tr[i];
        ah = fmaf(xv, Wx[((2 * 2 + 0) * INF + i) * HID + f], ah);
        ah = fmaf(tv, Wx[((2 * 2 + 1) * INF + i) * HID + f], ah);
    }
    float hrv = hr[(size_t)wave * HID + f];
    float thr = t1hr[(size_t)wave * HID + f];
#pragma unroll 8
    for (int j = 0; j < HID; ++j) {
        float hj = __shfl(hrv, j);
        float tj = __shfl(thr, j);
        ah = fmaf(hj, Wh[((2 * 2 + 0) * HID + j) * HID + f], ah);
        ah = fmaf(tj, Wh[((2 * 2 + 1) * HID + j) * HID + f], ah);
    }
    float Ht = tanhf(ah);
    float z = Zb[(size_t)wave * HID + f];
    float hv = h[(size_t)wave * HID + f];
    h[(size_t)wave * HID + f] = z * hv + (1.0f - z) * Ht;
}

// head: u = h @ head_W + head_b ; wave per node with shuffle reduce
__global__ __launch_bounds__(256) void k_head(
    const float* __restrict__ h, const float* __restrict__ hw,
    const float* __restrict__ hb, float* __restrict__ out, int n) {
    int wave = (int)((blockIdx.x * blockDim.x + threadIdx.x) >> 6);
    int f = threadIdx.x & 63;
    if (wave >= n) return;
    float hv = h[(size_t)wave * HID + f];
#pragma unroll
    for (int o = 0; o < OUTF; ++o) {
        float v = hv * hw[f * OUTF + o];
        for (int off = 32; off; off >>= 1) v += __shfl_down(v, off);
        if (f == 0) out[(size_t)wave * OUTF + o] = v + hb[o];
    }
}

extern "C" void kernel_launch(void* const* d_in, const int* in_sizes, int n_in,
                              void* d_out, int out_size, void* d_ws, size_t ws_size,
                              hipStream_t stream) {
    const float* X_seq = (const float*)d_in[0];    // [6, 20000, 11]
    const int* edge = (const int*)d_in[1];         // [2, 320000]
    const float* Wx = (const float*)d_in[2];       // [3, 2, 11, 64]
    const float* bx = (const float*)d_in[3];       // [3, 64]
    const float* Wh = (const float*)d_in[4];       // [3, 2, 64, 64]
    const float* bh = (const float*)d_in[5];       // [3, 64]
    const float* head_W = (const float*)d_in[6];   // [64, 3]
    const float* head_b = (const float*)d_in[7];   // [3]
    float* out = (float*)d_out;                    // [6, 20000, 3]

    const int* src = edge;
    const int* dst = edge + NE;

    // workspace layout (floats)
    float* ws = (float*)d_ws;
    float* dis  = ws;                 // N
    float* ew   = dis + NN;           // E
    float* xin  = ew + NE;            // N*11
    float* t1x  = xin + NN * INF;     // N*11
    float* h    = t1x + NN * INF;     // N*64
    float* t1h  = h + NN * HID;       // N*64
    float* t1hr = t1h + NN * HID;     // N*64
    float* Zb   = t1hr + NN * HID;    // N*64
    float* hr   = Zb + NN * HID;      // N*64

    // --- graph structure (once) ---
    hipMemsetAsync(dis, 0, NN * sizeof(float), stream);
    k_deg<<<(NE + 255) / 256, 256, 0, stream>>>(src, dis, NE);
    k_dis<<<(NN + 255) / 256, 256, 0, stream>>>(dis, NN);
    k_ew<<<(NE + 255) / 256, 256, 0, stream>>>(src, dst, dis, ew, NE);

    // h0 = 0
    hipMemsetAsync(h, 0, NN * HID * sizeof(float), stream);

    const int waves_grid = (NN * 64 + 255) / 256;  // wave-per-node kernels

    for (int t = 0; t < TSTEPS; ++t) {
        const float* Xt = X_seq + (size_t)t * NN * INF;

        // zero scatter accumulators
        hipMemsetAsync(t1x, 0, NN * INF * sizeof(float), stream);
        hipMemsetAsync(t1h, 0, NN * HID * sizeof(float), stream);
        hipMemsetAsync(t1hr, 0, NN * HID * sizeof(float), stream);

        // build x_in
        if (t == 0) {
            k_xin0<<<(NN * INF + 255) / 256, 256, 0, stream>>>(Xt, xin, NN);
        } else {
            const float* Xp = X_seq + (size_t)(t - 1) * NN * INF;
            const float* uprev = out + (size_t)(t - 1) * NN * OUTF;
            k_xin<<<(NN + 255) / 256, 256, 0, stream>>>(Xt, Xp, uprev, xin, NN);
        }

        // scatter x and h
        k_scat11<<<(NE * INF + 255) / 256, 256, 0, stream>>>(src, dst, ew, xin, t1x, NE);
        k_scat64<<<(NE * 64 + 255) / 256, 256, 0, stream>>>(src, dst, ew, h, t1h, NE);

        // Z, R gates; hr = h * R
        k_gates<<<waves_grid, 256, 0, stream>>>(xin, t1x, h, t1h, Wx, bx, Wh, bh, Zb, hr, NN);

        // scatter hr
        k_scat64<<<(NE * 64 + 255) / 256, 256, 0, stream>>>(src, dst, ew, hr, t1hr, NE);

        // candidate + blend (updates h in place)
        k_cand<<<waves_grid, 256, 0, stream>>>(xin, t1x, h, hr, t1hr, Wx, bx, Wh, bh, Zb, NN);

        // head projection -> out[t]
        k_head<<<waves_grid, 256, 0, stream>>>(h, head_W, head_b,
                                               out + (size_t)t * NN * OUTF, NN);
    }
}

// Round 2
// 972.631 us; speedup vs baseline: 1.6909x; 1.6909x over previous
//
#include <hip/hip_runtime.h>
#include <math.h>

#define TSTEPS 6
#define NN 20000
#define NE 320000
#define INF 11
#define XPAD 16   // padded feature stride for x-side buffers
#define HID 64
#define OUTF 3

// ---------------- graph-structure kernels (once per call) ----------------

__global__ void k_deg(const int* __restrict__ src, float* __restrict__ deg, int E) {
    int e = blockIdx.x * blockDim.x + threadIdx.x;
    if (e < E) atomicAdd(&deg[src[e]], 1.0f);
}

__global__ void k_dis(float* deg, int n) {
    int i = blockIdx.x * blockDim.x + threadIdx.x;
    if (i < n) {
        float d = deg[i];
        deg[i] = d > 0.0f ? rsqrtf(fmaxf(d, 1.0f)) : 0.0f;
    }
}

__global__ void k_ew(const int* __restrict__ src, const int* __restrict__ dst,
                     const float* __restrict__ dis, float* __restrict__ ew, int E) {
    int e = blockIdx.x * blockDim.x + threadIdx.x;
    if (e < E) ew[e] = -dis[src[e]] * dis[dst[e]];
}

__global__ void k_indeg(const int* __restrict__ dst, int* __restrict__ indeg, int E) {
    int e = blockIdx.x * blockDim.x + threadIdx.x;
    if (e < E) atomicAdd(&indeg[dst[e]], 1);
}

// exclusive scan of indeg[0..n) -> rowstart[0..n], single block of 1024
__global__ __launch_bounds__(1024) void k_scan(const int* __restrict__ in,
                                               int* __restrict__ out, int n) {
    __shared__ int buf[1024];
    __shared__ int carry;
    if (threadIdx.x == 0) carry = 0;
    __syncthreads();
    for (int base = 0; base < n; base += 1024) {
        int i = base + (int)threadIdx.x;
        int v = (i < n) ? in[i] : 0;
        buf[threadIdx.x] = v;
        __syncthreads();
        for (int off = 1; off < 1024; off <<= 1) {
            int t = (threadIdx.x >= (unsigned)off) ? buf[threadIdx.x - off] : 0;
            __syncthreads();
            buf[threadIdx.x] += t;
            __syncthreads();
        }
        if (i < n) out[i] = carry + buf[threadIdx.x] - v;  // exclusive
        __syncthreads();
        if (threadIdx.x == 0) carry += buf[1023];
        __syncthreads();
    }
    if (threadIdx.x == 0) out[n] = carry;
}

// fill CSR: permuted src + ew, bucketed by dst
__global__ void k_fill(const int* __restrict__ src, const int* __restrict__ dst,
                       const float* __restrict__ ew, int* __restrict__ cursor,
                       int* __restrict__ perm_src, float* __restrict__ perm_ew, int E) {
    int e = blockIdx.x * blockDim.x + threadIdx.x;
    if (e >= E) return;
    int pos = atomicAdd(&cursor[dst[e]], 1);
    perm_src[pos] = src[e];
    perm_ew[pos] = ew[e];
}

// ---------------- per-timestep kernels ----------------

// t == 0: x_in = X_seq[0], padded to stride 16
__global__ void k_xin0(const float* __restrict__ Xt, float* __restrict__ xin, int n) {
    int i = blockIdx.x * blockDim.x + threadIdx.x;
    if (i >= n) return;
    const float* xt = Xt + (size_t)i * INF;
    float* xo = xin + (size_t)i * XPAD;
#pragma unroll
    for (int k = 0; k < INF; ++k) xo[k] = xt[k];
#pragma unroll
    for (int k = INF; k < XPAD; ++k) xo[k] = 0.0f;
}

// t > 0: cols 3:6 <- u_prev, cols 8:11 <- (u_prev - X_prev[:,3:6]) / dt
__global__ void k_xin(const float* __restrict__ Xt, const float* __restrict__ Xp,
                      const float* __restrict__ uprev, float* __restrict__ xin, int n) {
    int i = blockIdx.x * blockDim.x + threadIdx.x;
    if (i >= n) return;
    const float* xt = Xt + (size_t)i * INF;
    const float* xp = Xp + (size_t)i * INF;
    const float* up = uprev + (size_t)i * OUTF;
    float* xo = xin + (size_t)i * XPAD;
    float dt = xt[6] - xp[6];
    float inv = 1.0f / dt;
    xo[0] = xt[0]; xo[1] = xt[1]; xo[2] = xt[2];
    xo[3] = up[0]; xo[4] = up[1]; xo[5] = up[2];
    xo[6] = xt[6]; xo[7] = xt[7];
    xo[8] = (up[0] - xp[3]) * inv;
    xo[9] = (up[1] - xp[4]) * inv;
    xo[10] = (up[2] - xp[5]) * inv;
    xo[11] = 0.0f; xo[12] = 0.0f; xo[13] = 0.0f; xo[14] = 0.0f; xo[15] = 0.0f;
}

// gather-SpMM, 16-wide padded features: one wave per node, 4 edges/iter
__global__ __launch_bounds__(256) void k_spmm16(
    const int* __restrict__ rowstart, const int* __restrict__ perm_src,
    const float* __restrict__ perm_ew, const float* __restrict__ x,
    float* __restrict__ out, int n) {
    int node = (int)((blockIdx.x * blockDim.x + threadIdx.x) >> 6);
    int lane = threadIdx.x & 63;
    int f = lane & 15;
    int eo = lane >> 4;  // 0..3
    if (node >= n) return;
    int s = rowstart[node], e = rowstart[node + 1];
    float acc = 0.0f;
    for (int p = s + eo; p < e; p += 4) {
        acc = fmaf(perm_ew[p], x[(size_t)perm_src[p] * XPAD + f], acc);
    }
    acc += __shfl_down(acc, 32);
    acc += __shfl_down(acc, 16);
    if (lane < 16) out[(size_t)node * XPAD + f] = acc;
}

// gather-SpMM, 64-wide: one wave per node, lane = feature, coalesced 256B/edge
__global__ __launch_bounds__(256) void k_spmm64(
    const int* __restrict__ rowstart, const int* __restrict__ perm_src,
    const float* __restrict__ perm_ew, const float* __restrict__ x,
    float* __restrict__ out, int n) {
    int node = (int)((blockIdx.x * blockDim.x + threadIdx.x) >> 6);
    int f = threadIdx.x & 63;
    if (node >= n) return;
    int s = rowstart[node], e = rowstart[node + 1];
    float acc0 = 0.0f, acc1 = 0.0f;
    int p = s;
    for (; p + 1 < e; p += 2) {
        int s0 = perm_src[p], s1 = perm_src[p + 1];
        float w0 = perm_ew[p], w1 = perm_ew[p + 1];
        acc0 = fmaf(w0, x[(size_t)s0 * HID + f], acc0);
        acc1 = fmaf(w1, x[(size_t)s1 * HID + f], acc1);
    }
    if (p < e) acc0 = fmaf(perm_ew[p], x[(size_t)perm_src[p] * HID + f], acc0);
    out[(size_t)node * HID + f] = acc0 + acc1;
}

// Z/R gate kernel: one wave per node, lane f = output channel.
__global__ __launch_bounds__(256) void k_gates(
    const float* __restrict__ xin, const float* __restrict__ t1x,
    const float* __restrict__ h, const float* __restrict__ t1h,
    const float* __restrict__ Wx, const float* __restrict__ bx,
    const float* __restrict__ Wh, const float* __restrict__ bh,
    float* __restrict__ Zb, float* __restrict__ hr, int n) {
    int wave = (int)((blockIdx.x * blockDim.x + threadIdx.x) >> 6);
    int f = threadIdx.x & 63;
    if (wave >= n) return;
    const float* xr = xin + (size_t)wave * XPAD;
    const float* tr = t1x + (size_t)wave * XPAD;
    float az = bx[0 * HID + f] + bh[0 * HID + f];
    float ar = bx[1 * HID + f] + bh[1 * HID + f];
#pragma unroll
    for (int i = 0; i < INF; ++i) {
        float xv = xr[i], tv = tr[i];
        az = fmaf(xv, Wx[((0 * 2 + 0) * INF + i) * HID + f], az);
        az = fmaf(tv, Wx[((0 * 2 + 1) * INF + i) * HID + f], az);
        ar = fmaf(xv, Wx[((1 * 2 + 0) * INF + i) * HID + f], ar);
        ar = fmaf(tv, Wx[((1 * 2 + 1) * INF + i) * HID + f], ar);
    }
    float hv = h[(size_t)wave * HID + f];
    float th = t1h[(size_t)wave * HID + f];
#pragma unroll 8
    for (int j = 0; j < HID; ++j) {
        float hj = __shfl(hv, j);
        float tj = __shfl(th, j);
        az = fmaf(hj, Wh[((0 * 2 + 0) * HID + j) * HID + f], az);
        az = fmaf(tj, Wh[((0 * 2 + 1) * HID + j) * HID + f], az);
        ar = fmaf(hj, Wh[((1 * 2 + 0) * HID + j) * HID + f], ar);
        ar = fmaf(tj, Wh[((1 * 2 + 1) * HID + j) * HID + f], ar);
    }
    float Z = 1.0f / (1.0f + expf(-az));
    float R = 1.0f / (1.0f + expf(-ar));
    Zb[(size_t)wave * HID + f] = Z;
    hr[(size_t)wave * HID + f] = hv * R;
}

// Candidate + blend + head: Ht = tanh(...), h_new = Z*h + (1-Z)*Ht, u = h_new @ head_W + head_b
__global__ __launch_bounds__(256) void k_cand(
    const float* __restrict__ xin, const float* __restrict__ t1x,
    float* __restrict__ h, const float* __restrict__ hr,
    const float* __restrict__ t1hr,
    const float* __restrict__ Wx, const float* __restrict__ bx,
    const float* __restrict__ Wh, const float* __restrict__ bh,
    const float* __restrict__ Zb,
    const float* __restrict__ hw, const float* __restrict__ hb,
    float* __restrict__ out, int n) {
    int wave = (int)((blockIdx.x * blockDim.x + threadIdx.x) >> 6);
    int f = threadIdx.x & 63;
    if (wave >= n) return;
    const float* xr = xin + (size_t)wave * XPAD;
    const float* tr = t1x + (size_t)wave * XPAD;
    float ah = bx[2 * HID + f] + bh[2 * HID + f];
#pragma unroll
    for (int i = 0; i < INF; ++i) {
        float xv = xr[i], tv = tr[i];
        ah = fmaf(xv, Wx[((2 * 2 + 0) * INF + i) * HID + f], ah);
        ah = fmaf(tv, Wx[((2 * 2 + 1) * INF + i) * HID + f], ah);
    }
    float hrv = hr[(size_t)wave * HID + f];
    float thr = t1hr[(size_t)wave * HID + f];
#pragma unroll 8
    for (int j = 0; j < HID; ++j) {
        float hj = __shfl(hrv, j);
        float tj = __shfl(thr, j);
        ah = fmaf(hj, Wh[((2 * 2 + 0) * HID + j) * HID + f], ah);
        ah = fmaf(tj, Wh[((2 * 2 + 1) * HID + j) * HID + f], ah);
    }
    float Ht = tanhf(ah);
    float z = Zb[(size_t)wave * HID + f];
    float hv = h[(size_t)wave * HID + f];
    float hnew = z * hv + (1.0f - z) * Ht;
    h[(size_t)wave * HID + f] = hnew;
    // fused head projection
#pragma unroll
    for (int o = 0; o < OUTF; ++o) {
        float v = hnew * hw[f * OUTF + o];
        for (int off = 32; off; off >>= 1) v += __shfl_down(v, off);
        if (f == 0) out[(size_t)wave * OUTF + o] = v + hb[o];
    }
}

extern "C" void kernel_launch(void* const* d_in, const int* in_sizes, int n_in,
                              void* d_out, int out_size, void* d_ws, size_t ws_size,
                              hipStream_t stream) {
    const float* X_seq = (const float*)d_in[0];    // [6, 20000, 11]
    const int* edge = (const int*)d_in[1];         // [2, 320000]
    const float* Wx = (const float*)d_in[2];       // [3, 2, 11, 64]
    const float* bx = (const float*)d_in[3];       // [3, 64]
    const float* Wh = (const float*)d_in[4];       // [3, 2, 64, 64]
    const float* bh = (const float*)d_in[5];       // [3, 64]
    const float* head_W = (const float*)d_in[6];   // [64, 3]
    const float* head_b = (const float*)d_in[7];   // [3]
    float* out = (float*)d_out;                    // [6, 20000, 3]

    const int* src = edge;
    const int* dst = edge + NE;

    // workspace layout
    float* ws = (float*)d_ws;
    float* dis      = ws;                         // N
    float* ew       = dis + NN;                   // E
    float* perm_ew  = ew + NE;                    // E
    float* xin      = perm_ew + NE;               // N*16
    float* t1x      = xin + NN * XPAD;            // N*16
    float* h        = t1x + NN * XPAD;            // N*64
    float* t1h      = h + NN * HID;               // N*64 (reused for t1hr)
    float* Zb       = t1h + NN * HID;             // N*64
    float* hr       = Zb + NN * HID;              // N*64
    int* indeg      = (int*)(hr + NN * HID);      // N
    int* rowstart   = indeg + NN;                 // N+1
    int* cursor     = rowstart + NN + 1;          // N
    int* perm_src   = cursor + NN;                // E

    // --- graph structure (once per call) ---
    hipMemsetAsync(dis, 0, NN * sizeof(float), stream);
    hipMemsetAsync(indeg, 0, NN * sizeof(int), stream);
    k_deg<<<(NE + 255) / 256, 256, 0, stream>>>(src, dis, NE);
    k_dis<<<(NN + 255) / 256, 256, 0, stream>>>(dis, NN);
    k_ew<<<(NE + 255) / 256, 256, 0, stream>>>(src, dst, dis, ew, NE);
    k_indeg<<<(NE + 255) / 256, 256, 0, stream>>>(dst, indeg, NE);
    k_scan<<<1, 1024, 0, stream>>>(indeg, rowstart, NN);
    hipMemcpyAsync(cursor, rowstart, NN * sizeof(int), hipMemcpyDeviceToDevice, stream);
    k_fill<<<(NE + 255) / 256, 256, 0, stream>>>(src, dst, ew, cursor, perm_src, perm_ew, NE);

    // h0 = 0
    hipMemsetAsync(h, 0, NN * HID * sizeof(float), stream);

    const int waves_grid = (NN * 64 + 255) / 256;  // wave-per-node kernels

    for (int t = 0; t < TSTEPS; ++t) {
        const float* Xt = X_seq + (size_t)t * NN * INF;

        // build x_in (padded to 16)
        if (t == 0) {
            k_xin0<<<(NN + 255) / 256, 256, 0, stream>>>(Xt, xin, NN);
        } else {
            const float* Xp = X_seq + (size_t)(t - 1) * NN * INF;
            const float* uprev = out + (size_t)(t - 1) * NN * OUTF;
            k_xin<<<(NN + 255) / 256, 256, 0, stream>>>(Xt, Xp, uprev, xin, NN);
        }

        // gather-aggregate x and h
        k_spmm16<<<waves_grid, 256, 0, stream>>>(rowstart, perm_src, perm_ew, xin, t1x, NN);
        k_spmm64<<<waves_grid, 256, 0, stream>>>(rowstart, perm_src, perm_ew, h, t1h, NN);

        // Z, R gates; hr = h * R
        k_gates<<<waves_grid, 256, 0, stream>>>(xin, t1x, h, t1h, Wx, bx, Wh, bh, Zb, hr, NN);

        // gather-aggregate hr (reuse t1h buffer — gates already consumed it)
        k_spmm64<<<waves_grid, 256, 0, stream>>>(rowstart, perm_src, perm_ew, hr, t1h, NN);

        // candidate + blend + fused head -> out[t]
        k_cand<<<waves_grid, 256, 0, stream>>>(xin, t1x, h, hr, t1h, Wx, bx, Wh, bh, Zb,
                                               head_W, head_b,
                                               out + (size_t)t * NN * OUTF, NN);
    }
}

// Round 3
// 953.284 us; speedup vs baseline: 1.7252x; 1.0203x over previous
//
#include <hip/hip_runtime.h>
#include <math.h>

#define TSTEPS 6
#define NN 20000
#define NE 320000
#define INF 11
#define XPAD 16   // padded feature stride for x-side buffers
#define HID 64
#define OUTF 3
#define NPW 4     // nodes per wave in gate/cand kernels

// ---------------- graph-structure kernels (once per call) ----------------

__global__ void k_deg(const int* __restrict__ src, float* __restrict__ deg, int E) {
    int e = blockIdx.x * blockDim.x + threadIdx.x;
    if (e < E) atomicAdd(&deg[src[e]], 1.0f);
}

__global__ void k_dis(float* deg, int n) {
    int i = blockIdx.x * blockDim.x + threadIdx.x;
    if (i < n) {
        float d = deg[i];
        deg[i] = d > 0.0f ? rsqrtf(fmaxf(d, 1.0f)) : 0.0f;
    }
}

__global__ void k_ew(const int* __restrict__ src, const int* __restrict__ dst,
                     const float* __restrict__ dis, float* __restrict__ ew, int E) {
    int e = blockIdx.x * blockDim.x + threadIdx.x;
    if (e < E) ew[e] = -dis[src[e]] * dis[dst[e]];
}

__global__ void k_indeg(const int* __restrict__ dst, int* __restrict__ indeg, int E) {
    int e = blockIdx.x * blockDim.x + threadIdx.x;
    if (e < E) atomicAdd(&indeg[dst[e]], 1);
}

// exclusive scan of indeg[0..n) -> rowstart[0..n], single block of 1024
__global__ __launch_bounds__(1024) void k_scan(const int* __restrict__ in,
                                               int* __restrict__ out, int n) {
    __shared__ int buf[1024];
    __shared__ int carry;
    if (threadIdx.x == 0) carry = 0;
    __syncthreads();
    for (int base = 0; base < n; base += 1024) {
        int i = base + (int)threadIdx.x;
        int v = (i < n) ? in[i] : 0;
        buf[threadIdx.x] = v;
        __syncthreads();
        for (int off = 1; off < 1024; off <<= 1) {
            int t = (threadIdx.x >= (unsigned)off) ? buf[threadIdx.x - off] : 0;
            __syncthreads();
            buf[threadIdx.x] += t;
            __syncthreads();
        }
        if (i < n) out[i] = carry + buf[threadIdx.x] - v;  // exclusive
        __syncthreads();
        if (threadIdx.x == 0) carry += buf[1023];
        __syncthreads();
    }
    if (threadIdx.x == 0) out[n] = carry;
}

// fill CSR: permuted src + ew, bucketed by dst
__global__ void k_fill(const int* __restrict__ src, const int* __restrict__ dst,
                       const float* __restrict__ ew, int* __restrict__ cursor,
                       int* __restrict__ perm_src, float* __restrict__ perm_ew, int E) {
    int e = blockIdx.x * blockDim.x + threadIdx.x;
    if (e >= E) return;
    int pos = atomicAdd(&cursor[dst[e]], 1);
    perm_src[pos] = src[e];
    perm_ew[pos] = ew[e];
}

// ---------------- per-timestep kernels ----------------

// t == 0: x_in = X_seq[0], padded to stride 16
__global__ void k_xin0(const float* __restrict__ Xt, float* __restrict__ xin, int n) {
    int i = blockIdx.x * blockDim.x + threadIdx.x;
    if (i >= n) return;
    const float* xt = Xt + (size_t)i * INF;
    float* xo = xin + (size_t)i * XPAD;
#pragma unroll
    for (int k = 0; k < INF; ++k) xo[k] = xt[k];
#pragma unroll
    for (int k = INF; k < XPAD; ++k) xo[k] = 0.0f;
}

// t > 0: cols 3:6 <- u_prev, cols 8:11 <- (u_prev - X_prev[:,3:6]) / dt
__global__ void k_xin(const float* __restrict__ Xt, const float* __restrict__ Xp,
                      const float* __restrict__ uprev, float* __restrict__ xin, int n) {
    int i = blockIdx.x * blockDim.x + threadIdx.x;
    if (i >= n) return;
    const float* xt = Xt + (size_t)i * INF;
    const float* xp = Xp + (size_t)i * INF;
    const float* up = uprev + (size_t)i * OUTF;
    float* xo = xin + (size_t)i * XPAD;
    float dt = xt[6] - xp[6];
    float inv = 1.0f / dt;
    xo[0] = xt[0]; xo[1] = xt[1]; xo[2] = xt[2];
    xo[3] = up[0]; xo[4] = up[1]; xo[5] = up[2];
    xo[6] = xt[6]; xo[7] = xt[7];
    xo[8] = (up[0] - xp[3]) * inv;
    xo[9] = (up[1] - xp[4]) * inv;
    xo[10] = (up[2] - xp[5]) * inv;
    xo[11] = 0.0f; xo[12] = 0.0f; xo[13] = 0.0f; xo[14] = 0.0f; xo[15] = 0.0f;
}

// gather-SpMM, 16-wide padded features: one wave per node, 4 edges/iter
__global__ __launch_bounds__(256) void k_spmm16(
    const int* __restrict__ rowstart, const int* __restrict__ perm_src,
    const float* __restrict__ perm_ew, const float* __restrict__ x,
    float* __restrict__ out, int n) {
    int node = (int)((blockIdx.x * blockDim.x + threadIdx.x) >> 6);
    int lane = threadIdx.x & 63;
    int f = lane & 15;
    int eo = lane >> 4;  // 0..3
    if (node >= n) return;
    int s = rowstart[node], e = rowstart[node + 1];
    float acc = 0.0f;
    for (int p = s + eo; p < e; p += 4) {
        acc = fmaf(perm_ew[p], x[(size_t)perm_src[p] * XPAD + f], acc);
    }
    acc += __shfl_down(acc, 32);
    acc += __shfl_down(acc, 16);
    if (lane < 16) out[(size_t)node * XPAD + f] = acc;
}

// gather-SpMM, 64-wide: one wave per node, lane = feature, coalesced 256B/edge
__global__ __launch_bounds__(256) void k_spmm64(
    const int* __restrict__ rowstart, const int* __restrict__ perm_src,
    const float* __restrict__ perm_ew, const float* __restrict__ x,
    float* __restrict__ out, int n) {
    int node = (int)((blockIdx.x * blockDim.x + threadIdx.x) >> 6);
    int f = threadIdx.x & 63;
    if (node >= n) return;
    int s = rowstart[node], e = rowstart[node + 1];
    float acc0 = 0.0f, acc1 = 0.0f;
    int p = s;
    for (; p + 1 < e; p += 2) {
        int s0 = perm_src[p], s1 = perm_src[p + 1];
        float w0 = perm_ew[p], w1 = perm_ew[p + 1];
        acc0 = fmaf(w0, x[(size_t)s0 * HID + f], acc0);
        acc1 = fmaf(w1, x[(size_t)s1 * HID + f], acc1);
    }
    if (p < e) acc0 = fmaf(perm_ew[p], x[(size_t)perm_src[p] * HID + f], acc0);
    out[(size_t)node * HID + f] = acc0 + acc1;
}

// Z/R gate kernel: NPW nodes per wave, lane f = output channel.
__global__ __launch_bounds__(256) void k_gates(
    const float* __restrict__ xin, const float* __restrict__ t1x,
    const float* __restrict__ h, const float* __restrict__ t1h,
    const float* __restrict__ Wx, const float* __restrict__ bx,
    const float* __restrict__ Wh, const float* __restrict__ bh,
    float* __restrict__ Zb, float* __restrict__ hr, int n) {
    int wbase = (int)((blockIdx.x * blockDim.x + threadIdx.x) >> 6) * NPW;
    int f = threadIdx.x & 63;
    if (wbase >= n) return;
    float b0z = bx[0 * HID + f] + bh[0 * HID + f];
    float b0r = bx[1 * HID + f] + bh[1 * HID + f];
    float az[NPW], ar[NPW], hv[NPW], th[NPW];
#pragma unroll
    for (int nn = 0; nn < NPW; ++nn) { az[nn] = b0z; ar[nn] = b0r; }
    // x-side: weight loads shared across the NPW nodes
#pragma unroll
    for (int i = 0; i < INF; ++i) {
        float wz0 = Wx[((0 * 2 + 0) * INF + i) * HID + f];
        float wz1 = Wx[((0 * 2 + 1) * INF + i) * HID + f];
        float wr0 = Wx[((1 * 2 + 0) * INF + i) * HID + f];
        float wr1 = Wx[((1 * 2 + 1) * INF + i) * HID + f];
#pragma unroll
        for (int nn = 0; nn < NPW; ++nn) {
            int node = wbase + nn;
            if (node >= n) break;
            float xv = xin[(size_t)node * XPAD + i];
            float tv = t1x[(size_t)node * XPAD + i];
            az[nn] = fmaf(xv, wz0, az[nn]);
            az[nn] = fmaf(tv, wz1, az[nn]);
            ar[nn] = fmaf(xv, wr0, ar[nn]);
            ar[nn] = fmaf(tv, wr1, ar[nn]);
        }
    }
#pragma unroll
    for (int nn = 0; nn < NPW; ++nn) {
        int node = wbase + nn;
        hv[nn] = (node < n) ? h[(size_t)node * HID + f] : 0.0f;
        th[nn] = (node < n) ? t1h[(size_t)node * HID + f] : 0.0f;
    }
#pragma unroll 8
    for (int j = 0; j < HID; ++j) {
        float wz0 = Wh[((0 * 2 + 0) * HID + j) * HID + f];
        float wz1 = Wh[((0 * 2 + 1) * HID + j) * HID + f];
        float wr0 = Wh[((1 * 2 + 0) * HID + j) * HID + f];
        float wr1 = Wh[((1 * 2 + 1) * HID + j) * HID + f];
#pragma unroll
        for (int nn = 0; nn < NPW; ++nn) {
            float hj = __shfl(hv[nn], j);
            float tj = __shfl(th[nn], j);
            az[nn] = fmaf(hj, wz0, az[nn]);
            az[nn] = fmaf(tj, wz1, az[nn]);
            ar[nn] = fmaf(hj, wr0, ar[nn]);
            ar[nn] = fmaf(tj, wr1, ar[nn]);
        }
    }
#pragma unroll
    for (int nn = 0; nn < NPW; ++nn) {
        int node = wbase + nn;
        if (node >= n) break;
        float Z = 1.0f / (1.0f + expf(-az[nn]));
        float R = 1.0f / (1.0f + expf(-ar[nn]));
        Zb[(size_t)node * HID + f] = Z;
        hr[(size_t)node * HID + f] = hv[nn] * R;
    }
}

// Candidate + blend + head, NPW nodes per wave
__global__ __launch_bounds__(256) void k_cand(
    const float* __restrict__ xin, const float* __restrict__ t1x,
    float* __restrict__ h, const float* __restrict__ hr,
    const float* __restrict__ t1hr,
    const float* __restrict__ Wx, const float* __restrict__ bx,
    const float* __restrict__ Wh, const float* __restrict__ bh,
    const float* __restrict__ Zb,
    const float* __restrict__ hw, const float* __restrict__ hb,
    float* __restrict__ out, int n) {
    int wbase = (int)((blockIdx.x * blockDim.x + threadIdx.x) >> 6) * NPW;
    int f = threadIdx.x & 63;
    if (wbase >= n) return;
    float b0 = bx[2 * HID + f] + bh[2 * HID + f];
    float ah[NPW], hrv[NPW], thr[NPW];
#pragma unroll
    for (int nn = 0; nn < NPW; ++nn) ah[nn] = b0;
#pragma unroll
    for (int i = 0; i < INF; ++i) {
        float w0 = Wx[((2 * 2 + 0) * INF + i) * HID + f];
        float w1 = Wx[((2 * 2 + 1) * INF + i) * HID + f];
#pragma unroll
        for (int nn = 0; nn < NPW; ++nn) {
            int node = wbase + nn;
            if (node >= n) break;
            float xv = xin[(size_t)node * XPAD + i];
            float tv = t1x[(size_t)node * XPAD + i];
            ah[nn] = fmaf(xv, w0, ah[nn]);
            ah[nn] = fmaf(tv, w1, ah[nn]);
        }
    }
#pragma unroll
    for (int nn = 0; nn < NPW; ++nn) {
        int node = wbase + nn;
        hrv[nn] = (node < n) ? hr[(size_t)node * HID + f] : 0.0f;
        thr[nn] = (node < n) ? t1hr[(size_t)node * HID + f] : 0.0f;
    }
#pragma unroll 8
    for (int j = 0; j < HID; ++j) {
        float w0 = Wh[((2 * 2 + 0) * HID + j) * HID + f];
        float w1 = Wh[((2 * 2 + 1) * HID + j) * HID + f];
#pragma unroll
        for (int nn = 0; nn < NPW; ++nn) {
            float hj = __shfl(hrv[nn], j);
            float tj = __shfl(thr[nn], j);
            ah[nn] = fmaf(hj, w0, ah[nn]);
            ah[nn] = fmaf(tj, w1, ah[nn]);
        }
    }
#pragma unroll
    for (int nn = 0; nn < NPW; ++nn) {
        int node = wbase + nn;
        if (node >= n) break;
        float Ht = tanhf(ah[nn]);
        float z = Zb[(size_t)node * HID + f];
        float hv = h[(size_t)node * HID + f];
        float hnew = z * hv + (1.0f - z) * Ht;
        h[(size_t)node * HID + f] = hnew;
#pragma unroll
        for (int o = 0; o < OUTF; ++o) {
            float v = hnew * hw[f * OUTF + o];
            for (int off = 32; off; off >>= 1) v += __shfl_down(v, off);
            if (f == 0) out[(size_t)node * OUTF + o] = v + hb[o];
        }
    }
}

extern "C" void kernel_launch(void* const* d_in, const int* in_sizes, int n_in,
                              void* d_out, int out_size, void* d_ws, size_t ws_size,
                              hipStream_t stream) {
    const float* X_seq = (const float*)d_in[0];    // [6, 20000, 11]
    const int* edge = (const int*)d_in[1];         // [2, 320000]
    const float* Wx = (const float*)d_in[2];       // [3, 2, 11, 64]
    const float* bx = (const float*)d_in[3];       // [3, 64]
    const float* Wh = (const float*)d_in[4];       // [3, 2, 64, 64]
    const float* bh = (const float*)d_in[5];       // [3, 64]
    const float* head_W = (const float*)d_in[6];   // [64, 3]
    const float* head_b = (const float*)d_in[7];   // [3]
    float* out = (float*)d_out;                    // [6, 20000, 3]

    const int* src = edge;
    const int* dst = edge + NE;

    // workspace layout
    float* ws = (float*)d_ws;
    float* dis      = ws;                         // N
    float* ew       = dis + NN;                   // E
    float* perm_ew  = ew + NE;                    // E
    float* xin      = perm_ew + NE;               // N*16
    float* t1x      = xin + NN * XPAD;            // N*16
    float* h        = t1x + NN * XPAD;            // N*64
    float* t1h      = h + NN * HID;               // N*64 (reused for t1hr)
    float* Zb       = t1h + NN * HID;             // N*64
    float* hr       = Zb + NN * HID;              // N*64
    int* indeg      = (int*)(hr + NN * HID);      // N
    int* rowstart   = indeg + NN;                 // N+1
    int* cursor     = rowstart + NN + 1;          // N
    int* perm_src   = cursor + NN;                // E

    // --- graph structure (once per call) ---
    hipMemsetAsync(dis, 0, NN * sizeof(float), stream);
    hipMemsetAsync(indeg, 0, NN * sizeof(int), stream);
    k_deg<<<(NE + 255) / 256, 256, 0, stream>>>(src, dis, NE);
    k_dis<<<(NN + 255) / 256, 256, 0, stream>>>(dis, NN);
    k_ew<<<(NE + 255) / 256, 256, 0, stream>>>(src, dst, dis, ew, NE);
    k_indeg<<<(NE + 255) / 256, 256, 0, stream>>>(dst, indeg, NE);
    k_scan<<<1, 1024, 0, stream>>>(indeg, rowstart, NN);
    hipMemcpyAsync(cursor, rowstart, NN * sizeof(int), hipMemcpyDeviceToDevice, stream);
    k_fill<<<(NE + 255) / 256, 256, 0, stream>>>(src, dst, ew, cursor, perm_src, perm_ew, NE);

    // h0 = 0
    hipMemsetAsync(h, 0, NN * HID * sizeof(float), stream);

    const int waves_grid = (NN * 64 + 255) / 256;                 // 1 node/wave kernels
    const int gates_grid = ((NN + NPW - 1) / NPW * 64 + 255) / 256;  // NPW nodes/wave

    for (int t = 0; t < TSTEPS; ++t) {
        const float* Xt = X_seq + (size_t)t * NN * INF;

        // build x_in (padded to 16)
        if (t == 0) {
            k_xin0<<<(NN + 255) / 256, 256, 0, stream>>>(Xt, xin, NN);
        } else {
            const float* Xp = X_seq + (size_t)(t - 1) * NN * INF;
            const float* uprev = out + (size_t)(t - 1) * NN * OUTF;
            k_xin<<<(NN + 255) / 256, 256, 0, stream>>>(Xt, Xp, uprev, xin, NN);
        }

        // gather-aggregate x and h
        k_spmm16<<<waves_grid, 256, 0, stream>>>(rowstart, perm_src, perm_ew, xin, t1x, NN);
        k_spmm64<<<waves_grid, 256, 0, stream>>>(rowstart, perm_src, perm_ew, h, t1h, NN);

        // Z, R gates; hr = h * R
        k_gates<<<gates_grid, 256, 0, stream>>>(xin, t1x, h, t1h, Wx, bx, Wh, bh, Zb, hr, NN);

        // gather-aggregate hr (reuse t1h buffer — gates already consumed it)
        k_spmm64<<<waves_grid, 256, 0, stream>>>(rowstart, perm_src, perm_ew, hr, t1h, NN);

        // candidate + blend + fused head -> out[t]
        k_cand<<<gates_grid, 256, 0, stream>>>(xin, t1x, h, hr, t1h, Wx, bx, Wh, bh, Zb,
                                               head_W, head_b,
                                               out + (size_t)t * NN * OUTF, NN);
    }
}

// Round 5
// 649.930 us; speedup vs baseline: 2.5305x; 1.4667x over previous
//
#include <hip/hip_runtime.h>
#include <math.h>

#define TSTEPS 6
#define NN 20000
#define NE 320000
#define INF 11
#define XPAD 16   // padded feature stride for x-side buffers
#define HID 64
#define OUTF 3
#define NPW 4     // nodes per wave in gate/cand kernels (NN % NPW == 0)

__device__ __forceinline__ float bcast(float v, int l) {
    return __uint_as_float(__builtin_amdgcn_readlane(__float_as_uint(v), l));
}

// overflow-safe fast tanh: e2 in (0,1], no inf/NaN for any finite a
__device__ __forceinline__ float tanh_safe(float a) {
    float e2 = __expf(-2.0f * fabsf(a));
    float t = (1.0f - e2) / (1.0f + e2);
    return copysignf(t, a);
}

// ---------------- graph-structure kernels (once per call) ----------------

__global__ void k_deg(const int* __restrict__ src, float* __restrict__ deg, int E) {
    int e = blockIdx.x * blockDim.x + threadIdx.x;
    if (e < E) atomicAdd(&deg[src[e]], 1.0f);
}

__global__ void k_dis(float* deg, int n) {
    int i = blockIdx.x * blockDim.x + threadIdx.x;
    if (i < n) {
        float d = deg[i];
        deg[i] = d > 0.0f ? rsqrtf(fmaxf(d, 1.0f)) : 0.0f;
    }
}

__global__ void k_ew(const int* __restrict__ src, const int* __restrict__ dst,
                     const float* __restrict__ dis, float* __restrict__ ew, int E) {
    int e = blockIdx.x * blockDim.x + threadIdx.x;
    if (e < E) ew[e] = -dis[src[e]] * dis[dst[e]];
}

__global__ void k_indeg(const int* __restrict__ dst, int* __restrict__ indeg, int E) {
    int e = blockIdx.x * blockDim.x + threadIdx.x;
    if (e < E) atomicAdd(&indeg[dst[e]], 1);
}

// exclusive scan of indeg[0..n) -> rowstart[0..n], single block of 1024
__global__ __launch_bounds__(1024) void k_scan(const int* __restrict__ in,
                                               int* __restrict__ out, int n) {
    __shared__ int buf[1024];
    __shared__ int carry;
    if (threadIdx.x == 0) carry = 0;
    __syncthreads();
    for (int base = 0; base < n; base += 1024) {
        int i = base + (int)threadIdx.x;
        int v = (i < n) ? in[i] : 0;
        buf[threadIdx.x] = v;
        __syncthreads();
        for (int off = 1; off < 1024; off <<= 1) {
            int t = (threadIdx.x >= (unsigned)off) ? buf[threadIdx.x - off] : 0;
            __syncthreads();
            buf[threadIdx.x] += t;
            __syncthreads();
        }
        if (i < n) out[i] = carry + buf[threadIdx.x] - v;  // exclusive
        __syncthreads();
        if (threadIdx.x == 0) carry += buf[1023];
        __syncthreads();
    }
    if (threadIdx.x == 0) out[n] = carry;
}

// fill CSR: permuted src + ew, bucketed by dst
__global__ void k_fill(const int* __restrict__ src, const int* __restrict__ dst,
                       const float* __restrict__ ew, int* __restrict__ cursor,
                       int* __restrict__ perm_src, float* __restrict__ perm_ew, int E) {
    int e = blockIdx.x * blockDim.x + threadIdx.x;
    if (e >= E) return;
    int pos = atomicAdd(&cursor[dst[e]], 1);
    perm_src[pos] = src[e];
    perm_ew[pos] = ew[e];
}

// ---------------- weight packing (once per call) ----------------
// gates: W4[j*64+f] = {Wz0[j][f], Wz1[j][f], Wr0[j][f], Wr1[j][f]}
__global__ void k_packh4(const float* __restrict__ Wh, float4* __restrict__ out) {
    int idx = blockIdx.x * blockDim.x + threadIdx.x;
    if (idx >= HID * HID) return;
    int j = idx >> 6, f = idx & 63;
    float4 v;
    v.x = Wh[((0 * 2 + 0) * HID + j) * HID + f];
    v.y = Wh[((0 * 2 + 1) * HID + j) * HID + f];
    v.z = Wh[((1 * 2 + 0) * HID + j) * HID + f];
    v.w = Wh[((1 * 2 + 1) * HID + j) * HID + f];
    out[idx] = v;
}
__global__ void k_packh2(const float* __restrict__ Wh, float2* __restrict__ out) {
    int idx = blockIdx.x * blockDim.x + threadIdx.x;
    if (idx >= HID * HID) return;
    int j = idx >> 6, f = idx & 63;
    float2 v;
    v.x = Wh[((2 * 2 + 0) * HID + j) * HID + f];
    v.y = Wh[((2 * 2 + 1) * HID + j) * HID + f];
    out[idx] = v;
}
__global__ void k_packx4(const float* __restrict__ Wx, float4* __restrict__ out) {
    int idx = blockIdx.x * blockDim.x + threadIdx.x;
    if (idx >= INF * HID) return;
    int i = idx >> 6, f = idx & 63;
    float4 v;
    v.x = Wx[((0 * 2 + 0) * INF + i) * HID + f];
    v.y = Wx[((0 * 2 + 1) * INF + i) * HID + f];
    v.z = Wx[((1 * 2 + 0) * INF + i) * HID + f];
    v.w = Wx[((1 * 2 + 1) * INF + i) * HID + f];
    out[idx] = v;
}
__global__ void k_packx2(const float* __restrict__ Wx, float2* __restrict__ out) {
    int idx = blockIdx.x * blockDim.x + threadIdx.x;
    if (idx >= INF * HID) return;
    int i = idx >> 6, f = idx & 63;
    float2 v;
    v.x = Wx[((2 * 2 + 0) * INF + i) * HID + f];
    v.y = Wx[((2 * 2 + 1) * INF + i) * HID + f];
    out[idx] = v;
}

// ---------------- per-timestep kernels ----------------

// t == 0: x_in = X_seq[0], padded to stride 16
__global__ void k_xin0(const float* __restrict__ Xt, float* __restrict__ xin, int n) {
    int i = blockIdx.x * blockDim.x + threadIdx.x;
    if (i >= n) return;
    const float* xt = Xt + (size_t)i * INF;
    float* xo = xin + (size_t)i * XPAD;
#pragma unroll
    for (int k = 0; k < INF; ++k) xo[k] = xt[k];
#pragma unroll
    for (int k = INF; k < XPAD; ++k) xo[k] = 0.0f;
}

// t > 0: cols 3:6 <- u_prev, cols 8:11 <- (u_prev - X_prev[:,3:6]) / dt
__global__ void k_xin(const float* __restrict__ Xt, const float* __restrict__ Xp,
                      const float* __restrict__ uprev, float* __restrict__ xin, int n) {
    int i = blockIdx.x * blockDim.x + threadIdx.x;
    if (i >= n) return;
    const float* xt = Xt + (size_t)i * INF;
    const float* xp = Xp + (size_t)i * INF;
    const float* up = uprev + (size_t)i * OUTF;
    float* xo = xin + (size_t)i * XPAD;
    float dt = xt[6] - xp[6];
    float inv = 1.0f / dt;
    xo[0] = xt[0]; xo[1] = xt[1]; xo[2] = xt[2];
    xo[3] = up[0]; xo[4] = up[1]; xo[5] = up[2];
    xo[6] = xt[6]; xo[7] = xt[7];
    xo[8] = (up[0] - xp[3]) * inv;
    xo[9] = (up[1] - xp[4]) * inv;
    xo[10] = (up[2] - xp[5]) * inv;
    xo[11] = 0.0f; xo[12] = 0.0f; xo[13] = 0.0f; xo[14] = 0.0f; xo[15] = 0.0f;
}

// gather-SpMM, 16-wide padded features: one wave per node, 4 edges/iter
__global__ __launch_bounds__(256) void k_spmm16(
    const int* __restrict__ rowstart, const int* __restrict__ perm_src,
    const float* __restrict__ perm_ew, const float* __restrict__ x,
    float* __restrict__ out, int n) {
    int node = (int)((blockIdx.x * blockDim.x + threadIdx.x) >> 6);
    int lane = threadIdx.x & 63;
    int f = lane & 15;
    int eo = lane >> 4;  // 0..3
    if (node >= n) return;
    int s = rowstart[node], e = rowstart[node + 1];
    float a0 = 0.0f, a1 = 0.0f;
    int p = s + eo;
    for (; p + 4 < e; p += 8) {
        a0 = fmaf(perm_ew[p], x[(size_t)perm_src[p] * XPAD + f], a0);
        a1 = fmaf(perm_ew[p + 4], x[(size_t)perm_src[p + 4] * XPAD + f], a1);
    }
    for (; p < e; p += 4)
        a0 = fmaf(perm_ew[p], x[(size_t)perm_src[p] * XPAD + f], a0);
    float acc = a0 + a1;
    acc += __shfl_down(acc, 32);
    acc += __shfl_down(acc, 16);
    if (lane < 16) out[(size_t)node * XPAD + f] = acc;
}

// gather-SpMM, 64-wide: one wave per node, lane = feature, 4 gathers in flight
__global__ __launch_bounds__(256) void k_spmm64(
    const int* __restrict__ rowstart, const int* __restrict__ perm_src,
    const float* __restrict__ perm_ew, const float* __restrict__ x,
    float* __restrict__ out, int n) {
    int node = (int)((blockIdx.x * blockDim.x + threadIdx.x) >> 6);
    int f = threadIdx.x & 63;
    if (node >= n) return;
    int s = rowstart[node], e = rowstart[node + 1];
    float a0 = 0.0f, a1 = 0.0f, a2 = 0.0f, a3 = 0.0f;
    int p = s;
    for (; p + 3 < e; p += 4) {
        int s0 = perm_src[p], s1 = perm_src[p + 1];
        int s2 = perm_src[p + 2], s3 = perm_src[p + 3];
        float w0 = perm_ew[p], w1 = perm_ew[p + 1];
        float w2 = perm_ew[p + 2], w3 = perm_ew[p + 3];
        a0 = fmaf(w0, x[(size_t)s0 * HID + f], a0);
        a1 = fmaf(w1, x[(size_t)s1 * HID + f], a1);
        a2 = fmaf(w2, x[(size_t)s2 * HID + f], a2);
        a3 = fmaf(w3, x[(size_t)s3 * HID + f], a3);
    }
    for (; p < e; ++p)
        a0 = fmaf(perm_ew[p], x[(size_t)perm_src[p] * HID + f], a0);
    out[(size_t)node * HID + f] = (a0 + a1) + (a2 + a3);
}

// Z/R gate kernel: NPW nodes per wave, lane f = output channel, packed float4 weights.
__global__ __launch_bounds__(256) void k_gates(
    const float* __restrict__ xin, const float* __restrict__ t1x,
    const float* __restrict__ h, const float* __restrict__ t1h,
    const float4* __restrict__ Wx4, const float* __restrict__ bx,
    const float4* __restrict__ Wh4, const float* __restrict__ bh,
    float* __restrict__ Zb, float* __restrict__ hr, int n) {
    int wbase = (int)((blockIdx.x * blockDim.x + threadIdx.x) >> 6) * NPW;
    int lane = threadIdx.x & 63;
    int f = lane;
    if (wbase >= n) return;
    // coalesced x-side rows: lane l holds xin[wbase*16 + l] (NPW*XPAD == 64)
    float xrow = xin[(size_t)wbase * XPAD + lane];
    float trow = t1x[(size_t)wbase * XPAD + lane];
    float b0z = bx[0 * HID + f] + bh[0 * HID + f];
    float b0r = bx[1 * HID + f] + bh[1 * HID + f];
    float az[NPW], ar[NPW], hv[NPW], th[NPW];
#pragma unroll
    for (int nn = 0; nn < NPW; ++nn) { az[nn] = b0z; ar[nn] = b0r; }
#pragma unroll
    for (int nn = 0; nn < NPW; ++nn) {
        hv[nn] = h[(size_t)(wbase + nn) * HID + f];
        th[nn] = t1h[(size_t)(wbase + nn) * HID + f];
    }
    // x-side: one float4 weight load per i
#pragma unroll
    for (int i = 0; i < INF; ++i) {
        float4 w = Wx4[i * HID + f];
#pragma unroll
        for (int nn = 0; nn < NPW; ++nn) {
            float xv = bcast(xrow, nn * XPAD + i);
            float tv = bcast(trow, nn * XPAD + i);
            az[nn] = fmaf(xv, w.x, fmaf(tv, w.y, az[nn]));
            ar[nn] = fmaf(xv, w.z, fmaf(tv, w.w, ar[nn]));
        }
    }
    // h-side: one float4 weight load per j
#pragma unroll 8
    for (int j = 0; j < HID; ++j) {
        float4 w = Wh4[j * HID + f];
#pragma unroll
        for (int nn = 0; nn < NPW; ++nn) {
            float hj = bcast(hv[nn], j);
            float tj = bcast(th[nn], j);
            az[nn] = fmaf(hj, w.x, fmaf(tj, w.y, az[nn]));
            ar[nn] = fmaf(hj, w.z, fmaf(tj, w.w, ar[nn]));
        }
    }
#pragma unroll
    for (int nn = 0; nn < NPW; ++nn) {
        float Z = 1.0f / (1.0f + __expf(-az[nn]));
        float R = 1.0f / (1.0f + __expf(-ar[nn]));
        Zb[(size_t)(wbase + nn) * HID + f] = Z;
        hr[(size_t)(wbase + nn) * HID + f] = hv[nn] * R;
    }
}

// Candidate + blend + head: packed float2 weights, NPW nodes per wave
__global__ __launch_bounds__(256) void k_cand(
    const float* __restrict__ xin, const float* __restrict__ t1x,
    float* __restrict__ h, const float* __restrict__ hr,
    const float* __restrict__ t1hr,
    const float2* __restrict__ Wx2, const float* __restrict__ bx,
    const float2* __restrict__ Wh2, const float* __restrict__ bh,
    const float* __restrict__ Zb,
    const float* __restrict__ hw, const float* __restrict__ hb,
    float* __restrict__ out, int n) {
    int wbase = (int)((blockIdx.x * blockDim.x + threadIdx.x) >> 6) * NPW;
    int lane = threadIdx.x & 63;
    int f = lane;
    if (wbase >= n) return;
    float xrow = xin[(size_t)wbase * XPAD + lane];
    float trow = t1x[(size_t)wbase * XPAD + lane];
    float b0 = bx[2 * HID + f] + bh[2 * HID + f];
    float ah[NPW], hrv[NPW], thr[NPW];
#pragma unroll
    for (int nn = 0; nn < NPW; ++nn) ah[nn] = b0;
#pragma unroll
    for (int nn = 0; nn < NPW; ++nn) {
        hrv[nn] = hr[(size_t)(wbase + nn) * HID + f];
        thr[nn] = t1hr[(size_t)(wbase + nn) * HID + f];
    }
#pragma unroll
    for (int i = 0; i < INF; ++i) {
        float2 w = Wx2[i * HID + f];
#pragma unroll
        for (int nn = 0; nn < NPW; ++nn) {
            float xv = bcast(xrow, nn * XPAD + i);
            float tv = bcast(trow, nn * XPAD + i);
            ah[nn] = fmaf(xv, w.x, fmaf(tv, w.y, ah[nn]));
        }
    }
#pragma unroll 8
    for (int j = 0; j < HID; ++j) {
        float2 w = Wh2[j * HID + f];
#pragma unroll
        for (int nn = 0; nn < NPW; ++nn) {
            float hj = bcast(hrv[nn], j);
            float tj = bcast(thr[nn], j);
            ah[nn] = fmaf(hj, w.x, fmaf(tj, w.y, ah[nn]));
        }
    }
#pragma unroll
    for (int nn = 0; nn < NPW; ++nn) {
        int node = wbase + nn;
        float Ht = tanh_safe(ah[nn]);
        float z = Zb[(size_t)node * HID + f];
        float hv = h[(size_t)node * HID + f];
        float hnew = z * hv + (1.0f - z) * Ht;
        h[(size_t)node * HID + f] = hnew;
#pragma unroll
        for (int o = 0; o < OUTF; ++o) {
            float v = hnew * hw[f * OUTF + o];
            for (int off = 32; off; off >>= 1) v += __shfl_down(v, off);
            if (f == 0) out[(size_t)node * OUTF + o] = v + hb[o];
        }
    }
}

extern "C" void kernel_launch(void* const* d_in, const int* in_sizes, int n_in,
                              void* d_out, int out_size, void* d_ws, size_t ws_size,
                              hipStream_t stream) {
    const float* X_seq = (const float*)d_in[0];    // [6, 20000, 11]
    const int* edge = (const int*)d_in[1];         // [2, 320000]
    const float* Wx = (const float*)d_in[2];       // [3, 2, 11, 64]
    const float* bx = (const float*)d_in[3];       // [3, 64]
    const float* Wh = (const float*)d_in[4];       // [3, 2, 64, 64]
    const float* bh = (const float*)d_in[5];       // [3, 64]
    const float* head_W = (const float*)d_in[6];   // [64, 3]
    const float* head_b = (const float*)d_in[7];   // [3]
    float* out = (float*)d_out;                    // [6, 20000, 3]

    const int* src = edge;
    const int* dst = edge + NE;

    // workspace layout (floats). Packed weights first for 16B alignment.
    float* ws = (float*)d_ws;
    float4* Wh4g   = (float4*)ws;                       // 4096 float4 = 16384 f
    float4* Wx4g   = (float4*)(ws + 16384);             // 704 float4  = 2816 f
    float2* Wh2c   = (float2*)(ws + 16384 + 2816);      // 4096 float2 = 8192 f
    float2* Wx2c   = (float2*)(ws + 16384 + 2816 + 8192); // 704 float2 = 1408 f
    float* fbase   = ws + 16384 + 2816 + 8192 + 1408;   // = ws + 28800
    float* dis      = fbase;                      // N
    float* ew       = dis + NN;                   // E
    float* perm_ew  = ew + NE;                    // E
    float* xin      = perm_ew + NE;               // N*16
    float* t1x      = xin + NN * XPAD;            // N*16
    float* h        = t1x + NN * XPAD;            // N*64
    float* t1h      = h + NN * HID;               // N*64 (reused for t1hr)
    float* Zb       = t1h + NN * HID;             // N*64
    float* hr       = Zb + NN * HID;              // N*64
    int* indeg      = (int*)(hr + NN * HID);      // N
    int* rowstart   = indeg + NN;                 // N+1
    int* cursor     = rowstart + NN + 1;          // N
    int* perm_src   = cursor + NN;                // E

    // --- graph structure + weight packing (once per call) ---
    hipMemsetAsync(dis, 0, NN * sizeof(float), stream);
    hipMemsetAsync(indeg, 0, NN * sizeof(int), stream);
    k_deg<<<(NE + 255) / 256, 256, 0, stream>>>(src, dis, NE);
    k_dis<<<(NN + 255) / 256, 256, 0, stream>>>(dis, NN);
    k_ew<<<(NE + 255) / 256, 256, 0, stream>>>(src, dst, dis, ew, NE);
    k_indeg<<<(NE + 255) / 256, 256, 0, stream>>>(dst, indeg, NE);
    k_scan<<<1, 1024, 0, stream>>>(indeg, rowstart, NN);
    hipMemcpyAsync(cursor, rowstart, NN * sizeof(int), hipMemcpyDeviceToDevice, stream);
    k_fill<<<(NE + 255) / 256, 256, 0, stream>>>(src, dst, ew, cursor, perm_src, perm_ew, NE);
    k_packh4<<<(HID * HID + 255) / 256, 256, 0, stream>>>(Wh, Wh4g);
    k_packh2<<<(HID * HID + 255) / 256, 256, 0, stream>>>(Wh, Wh2c);
    k_packx4<<<(INF * HID + 255) / 256, 256, 0, stream>>>(Wx, Wx4g);
    k_packx2<<<(INF * HID + 255) / 256, 256, 0, stream>>>(Wx, Wx2c);

    // h0 = 0
    hipMemsetAsync(h, 0, NN * HID * sizeof(float), stream);

    const int waves_grid = (NN * 64 + 255) / 256;                    // 1 node/wave
    const int gates_grid = ((NN + NPW - 1) / NPW * 64 + 255) / 256;  // NPW nodes/wave

    for (int t = 0; t < TSTEPS; ++t) {
        const float* Xt = X_seq + (size_t)t * NN * INF;

        if (t == 0) {
            k_xin0<<<(NN + 255) / 256, 256, 0, stream>>>(Xt, xin, NN);
        } else {
            const float* Xp = X_seq + (size_t)(t - 1) * NN * INF;
            const float* uprev = out + (size_t)(t - 1) * NN * OUTF;
            k_xin<<<(NN + 255) / 256, 256, 0, stream>>>(Xt, Xp, uprev, xin, NN);
        }

        k_spmm16<<<waves_grid, 256, 0, stream>>>(rowstart, perm_src, perm_ew, xin, t1x, NN);
        k_spmm64<<<waves_grid, 256, 0, stream>>>(rowstart, perm_src, perm_ew, h, t1h, NN);

        k_gates<<<gates_grid, 256, 0, stream>>>(xin, t1x, h, t1h, Wx4g, bx, Wh4g, bh,
                                                Zb, hr, NN);

        k_spmm64<<<waves_grid, 256, 0, stream>>>(rowstart, perm_src, perm_ew, hr, t1h, NN);

        k_cand<<<gates_grid, 256, 0, stream>>>(xin, t1x, h, hr, t1h, Wx2c, bx, Wh2c, bh,
                                               Zb, head_W, head_b,
                                               out + (size_t)t * NN * OUTF, NN);
    }
}